// Round 3
// baseline (2555.627 us; speedup 1.0000x reference)
//
#include <hip/hip_runtime.h>

#define N_NODES 10000
#define IN_DIM 128
#define EDGE_DIM 64
#define HID_DIM 256
#define OUT_DIM 128
#define N_EDGES 640000

// Data contract (verified R6): fp32 buffers (values bf16-rounded), int32
// edge_index, fp32 output, atomic scatter into d_out.
// Barrier-free wave-owned structure (R2) with the h-realignment FIXED:
// R2's single-shfl tile select used the SOURCE lane's q to pick the tile;
// the tile index depends on the TARGET's q>>1, and one shfl per register
// provably cannot serve both targets of a source lane (they need different
// tiles). Fix: two shfls per register + target-side select (32 bpermute +
// 16 cndmask per group — noise vs 96 MFMAs).
// LDS = 49152 + 32768 = 81920 B exactly -> 2 blocks/CU (2x81920 = 160 KiB).

typedef __bf16 bf16x8 __attribute__((ext_vector_type(8)));
typedef float f32x4 __attribute__((ext_vector_type(4)));

// pre-rounded fp32 pair -> packed bf16 pair (exact: low mantissa bits are 0)
static __device__ __forceinline__ unsigned pk_pre(float lo, float hi) {
    return (__builtin_bit_cast(unsigned, lo) >> 16) |
           (__builtin_bit_cast(unsigned, hi) & 0xFFFF0000u);
}
// RNE f2bf for freshly computed values (h epilogue) — matches passing R6 math
static __device__ __forceinline__ unsigned short f2bf(float f) {
    unsigned u = __builtin_bit_cast(unsigned, f);
    u = (u + 0x7fffu + ((u >> 16) & 1u)) >> 16;
    return (unsigned short)u;
}

__global__ void zero_kernel(float* __restrict__ out) {
    int t = blockIdx.x * 256 + threadIdx.x;
    if (t < 320000) ((float4*)out)[t] = make_float4(0.f, 0.f, 0.f, 0.f);
}

// lane (e16,q) loads the 48 floats of its own GEMM1 B-fragments:
// m[e16][ks*32 + q*8 .. +7] for ks=0..5 (k<128 from x[src], k>=128 from ea).
static __device__ __forceinline__ void gather_m(const float* __restrict__ x,
                                                const float* __restrict__ ea,
                                                int src, int g, int e16, int q,
                                                float4* raw) {
    const float* xr = x + (size_t)src * 128 + q * 8;
    const float* er = ea + (size_t)(g * 16 + e16) * 64 + q * 8;
    #pragma unroll
    for (int ks = 0; ks < 4; ++ks) {
        raw[ks * 2 + 0] = *(const float4*)(xr + ks * 32);
        raw[ks * 2 + 1] = *(const float4*)(xr + ks * 32 + 4);
    }
    #pragma unroll
    for (int ks = 0; ks < 2; ++ks) {
        raw[8 + ks * 2 + 0] = *(const float4*)(er + ks * 32);
        raw[8 + ks * 2 + 1] = *(const float4*)(er + ks * 32 + 4);
    }
}

__global__ __launch_bounds__(256, 2) void gine_wave(
    const int* __restrict__ ei,
    const float* __restrict__ x,
    const float* __restrict__ ea,
    const float* __restrict__ W1,
    const float* __restrict__ b1,
    const float* __restrict__ W2,
    const float* __restrict__ b2,
    float* __restrict__ out)
{
    // XOR-swizzled, pad-free weight tiles. 49,152 + 32,768 = 81,920 B exactly.
    __shared__ __align__(16) unsigned sW1u[128 * 96];  // W1 hid-half: [128 hid][96 k-pairs]
    __shared__ __align__(16) unsigned sW2u[128 * 64];  // W2 k-half:  [128 out][64 k-pairs]

    const int tid  = threadIdx.x;
    const int hb   = blockIdx.x & 1;
    const int bseq = blockIdx.x >> 1;            // 0..255

    // ---- stage W1 half (swizzle: uint col ^= (row&7)<<2; keeps 16B blocks intact) ----
    for (int i = tid; i < 128 * 96; i += 256) {
        int r = i / 96, c2 = i - r * 96;
        const float* w = W1 + (size_t)(hb * 128 + r) * 192 + c2 * 2;
        sW1u[r * 96 + (c2 ^ ((r & 7) << 2))] = pk_pre(w[0], w[1]);
    }
    // ---- stage W2 half (rows = out dim, k-half cols) ----
    for (int i = tid; i < 128 * 64; i += 256) {
        int r = i / 64, c2 = i - r * 64;
        const float* w = W2 + (size_t)r * 256 + hb * 128 + c2 * 2;
        sW2u[r * 64 + (c2 ^ ((r & 7) << 2))] = pk_pre(w[0], w[1]);
    }

    const int lane = tid & 63;
    const int e16  = lane & 15;
    const int q    = lane >> 4;
    const int wv   = tid >> 6;
    const int rsw  = (e16 & 7) << 2;             // A-frag read swizzle (row = *16+e16)

    // ---- bias fragments in registers (bias added AFTER accumulation, as in R6) ----
    f32x4 b1f[8], b2f[8];
    #pragma unroll
    for (int t = 0; t < 8; ++t) {
        b1f[t] = *(const f32x4*)(b1 + hb * 128 + t * 16 + q * 4);
        b2f[t] = hb ? (f32x4){0.f, 0.f, 0.f, 0.f}
                    : *(const f32x4*)(b2 + t * 16 + q * 4);
    }

    __syncthreads();   // the only barrier: weights staged

    const int wgid = bseq * 4 + wv;              // 0..1023 per hb

    // ---- prologue: indices + gather for first group ----
    int g = wgid;
    int dstc = ei[N_EDGES + g * 16 + e16];
    float4 raw[12];
    gather_m(x, ea, ei[g * 16 + e16], g, e16, q, raw);

    for (; g < 40000; g += 1024) {
        const int gn   = g + 1024;
        const int gcl  = (gn < 40000) ? gn : g;  // clamp: last-iter prefetch is harmless

        // prefetch next group's indices (latency hidden under GEMM1)
        int srcn = ei[gcl * 16 + e16];
        int dstn = ei[N_EDGES + gcl * 16 + e16];

        // ---- GEMM1: h_pre[16 edges][128 hid-half], 8 tiles x 6 k-steps ----
        f32x4 acc1[8];
        #pragma unroll
        for (int t = 0; t < 8; ++t) acc1[t] = (f32x4){0.f, 0.f, 0.f, 0.f};
        #pragma unroll
        for (int ks = 0; ks < 6; ++ks) {
            float4 a = raw[ks * 2], b = raw[ks * 2 + 1];
            int4 bi;
            bi.x = (int)pk_pre(a.x, a.y);
            bi.y = (int)pk_pre(a.z, a.w);
            bi.z = (int)pk_pre(b.x, b.y);
            bi.w = (int)pk_pre(b.z, b.w);
            bf16x8 bfrag = __builtin_bit_cast(bf16x8, bi);
            #pragma unroll
            for (int mt = 0; mt < 8; ++mt) {
                const unsigned* ap = sW1u + (mt * 16 + e16) * 96 + ((ks * 16 + q * 4) ^ rsw);
                bf16x8 afrag = __builtin_bit_cast(bf16x8, *(const int4*)ap);
                acc1[mt] = __builtin_amdgcn_mfma_f32_16x16x32_bf16(afrag, bfrag, acc1[mt], 0, 0, 0);
            }
        }

        // ---- epilogue: relu(acc1 + b1) -> packed bf16 pairs ----
        // lane (e16,q) holds h[edge=e16][hid = mt*16 + q*4 + r], pu0=r0|r1, pu1=r2|r3
        unsigned pu0[8], pu1[8];
        #pragma unroll
        for (int mt = 0; mt < 8; ++mt) {
            float v0 = fmaxf(acc1[mt][0] + b1f[mt][0], 0.f);
            float v1 = fmaxf(acc1[mt][1] + b1f[mt][1], 0.f);
            float v2 = fmaxf(acc1[mt][2] + b1f[mt][2], 0.f);
            float v3 = fmaxf(acc1[mt][3] + b1f[mt][3], 0.f);
            pu0[mt] = (unsigned)f2bf(v0) | ((unsigned)f2bf(v1) << 16);
            pu1[mt] = (unsigned)f2bf(v2) | ((unsigned)f2bf(v3) << 16);
        }

        // ---- issue next group's gather NOW (before GEMM2, before atomics) ----
        // Gather stays OLDER than the scatter atomics, so next iter's vmcnt
        // wait for raw never drains the atomics.
        gather_m(x, ea, srcn, gcl, e16, q, raw);

        // ---- GEMM2: msg[16 edges][128 out] from h via shfl realign ----
        // Target B-frag (e16,q,kb) needs h[e16][kb*32+q*8+j]:
        //   j=0..3 from source lane sa   = (q&1)*32 + e16  (rows (q&1)*8+0..3)
        //   j=4..7 from source lane sa+16                  (rows (q&1)*8+4..7)
        //   tile mt = 2kb + (q>>1)  — TARGET's q, so select AFTER the shfl.
        f32x4 acc2[8];
        #pragma unroll
        for (int t = 0; t < 8; ++t) acc2[t] = (f32x4){0.f, 0.f, 0.f, 0.f};
        const int qh = q >> 1;
        const int sa = (q & 1) * 32 + e16;
        #pragma unroll
        for (int kb = 0; kb < 4; ++kb) {
            const int lo0 = (int)pu0[2 * kb],     lo1 = (int)pu1[2 * kb];
            const int hi0 = (int)pu0[2 * kb + 1], hi1 = (int)pu1[2 * kb + 1];
            int4 bi;
            {
                int a0 = __shfl(lo0, sa, 64),      a1 = __shfl(hi0, sa, 64);
                int b0 = __shfl(lo1, sa, 64),      b1_ = __shfl(hi1, sa, 64);
                int c0 = __shfl(lo0, sa + 16, 64), c1 = __shfl(hi0, sa + 16, 64);
                int d0 = __shfl(lo1, sa + 16, 64), d1 = __shfl(hi1, sa + 16, 64);
                bi.x = qh ? a1 : a0;
                bi.y = qh ? b1_ : b0;
                bi.z = qh ? c1 : c0;
                bi.w = qh ? d1 : d0;
            }
            bf16x8 bfrag = __builtin_bit_cast(bf16x8, bi);
            #pragma unroll
            for (int ot = 0; ot < 8; ++ot) {
                const unsigned* ap = sW2u + (ot * 16 + e16) * 64 + ((kb * 16 + q * 4) ^ rsw);
                bf16x8 afrag = __builtin_bit_cast(bf16x8, *(const int4*)ap);
                acc2[ot] = __builtin_amdgcn_mfma_f32_16x16x32_bf16(afrag, bfrag, acc2[ot], 0, 0, 0);
            }
        }

        // ---- scatter: direct per-lane atomics, never waited on ----
        // lane (e16,q): msg[edge e16][out = ot*16 + q*4 + r]
        {
            float* ob = out + (size_t)dstc * 128 + q * 4;
            #pragma unroll
            for (int ot = 0; ot < 8; ++ot) {
                unsafeAtomicAdd(ob + ot * 16 + 0, acc2[ot][0] + b2f[ot][0]);
                unsafeAtomicAdd(ob + ot * 16 + 1, acc2[ot][1] + b2f[ot][1]);
                unsafeAtomicAdd(ob + ot * 16 + 2, acc2[ot][2] + b2f[ot][2]);
                unsafeAtomicAdd(ob + ot * 16 + 3, acc2[ot][3] + b2f[ot][3]);
            }
        }
        dstc = dstn;
    }
}

extern "C" void kernel_launch(void* const* d_in, const int* in_sizes, int n_in,
                              void* d_out, int out_size, void* d_ws, size_t ws_size,
                              hipStream_t stream) {
    const float* x  = (const float*)d_in[0];
    const int*   ei = (const int*)d_in[1];
    const float* ea = (const float*)d_in[2];
    const float* W1 = (const float*)d_in[3];
    const float* b1 = (const float*)d_in[4];
    const float* W2 = (const float*)d_in[5];
    const float* b2 = (const float*)d_in[6];
    float* out = (float*)d_out;

    zero_kernel<<<1250, 256, 0, stream>>>(out);
    gine_wave<<<512, 256, 0, stream>>>(ei, x, ea, W1, b1, W2, b2, out);
}

// Round 5
// 725.754 us; speedup vs baseline: 3.5213x; 3.5213x over previous
//
#include <hip/hip_runtime.h>

#define N_NODES 10000
#define IN_DIM 128
#define EDGE_DIM 64
#define HID_DIM 256
#define OUT_DIM 128
#define N_EDGES 640000

// Data contract (verified R6): fp32 buffers (values bf16-rounded), int32
// edge_index, fp32 output, atomic scatter into d_out.
// R4 (resubmit; R4 bench was an infra timeout, kernel never ran):
// R1's block-cooperative memory patterns (coalesced staged gather,
// row-contiguous scatter) + raw-barrier pipeline:
//  - 2 raw s_barriers/iter (lgkmcnt only; atomics NEVER drained)
//  - double-buffered sMu, gather for g+1 issued at top of iter g
//  - wave-private sMsg (wave scatters the rows it computed) -> no barrier
//  - XOR-swizzled pad-free LDS (R3-verified) -> aligned ds_read_b128
// LDS total ~74.8 KB -> 2 blocks/CU.

typedef __bf16 bf16x8 __attribute__((ext_vector_type(8)));
typedef float f32x4 __attribute__((ext_vector_type(4)));

// pre-rounded fp32 pair -> packed bf16 pair (exact: low mantissa bits are 0)
static __device__ __forceinline__ unsigned pk_pre(float lo, float hi) {
    return (__builtin_bit_cast(unsigned, lo) >> 16) |
           (__builtin_bit_cast(unsigned, hi) & 0xFFFF0000u);
}
// RNE f2bf for freshly computed values (h epilogue)
static __device__ __forceinline__ unsigned short f2bf(float f) {
    unsigned u = __builtin_bit_cast(unsigned, f);
    u = (u + 0x7fffu + ((u >> 16) & 1u)) >> 16;
    return (unsigned short)u;
}

__global__ void zero_kernel(float* __restrict__ out) {
    int t = blockIdx.x * 256 + threadIdx.x;
    if (t < 320000) ((float4*)out)[t] = make_float4(0.f, 0.f, 0.f, 0.f);
}

#define FENCE_LGKM()  asm volatile("s_waitcnt lgkmcnt(0)" ::: "memory")
#define SCHED_FENCE() __builtin_amdgcn_sched_barrier(0)
#define BLOCK_BAR()   do { FENCE_LGKM(); SCHED_FENCE(); \
                           __builtin_amdgcn_s_barrier(); SCHED_FENCE(); } while (0)

__global__ __launch_bounds__(256, 2) void gine_pipe(
    const int* __restrict__ ei,
    const float* __restrict__ x,
    const float* __restrict__ ea,
    const float* __restrict__ W1,
    const float* __restrict__ b1,
    const float* __restrict__ W2,
    const float* __restrict__ b2,
    float* __restrict__ out)
{
    // XOR-swizzled pad-free tiles (uint col ^= (row&7)<<2 keeps 16B blocks).
    __shared__ __align__(16) unsigned sW1u[128 * 96];   // 49,152 B  W1 hid-half
    __shared__ __align__(16) unsigned sMu[2][16 * 96];  // 12,288 B  m dbuf
    __shared__ __align__(16) unsigned sHuU[16 * 64];    //  4,096 B  h (bf16 pairs)
    __shared__ __align__(16) float    sMsg[16 * 132];   //  8,448 B  msg (wave-private rows)
    __shared__ float sB1[128];
    __shared__ __align__(16) int sSE[2][16], sDE[2][16];

    const int tid  = threadIdx.x;
    const int hb   = blockIdx.x & 1;
    const int bseq = blockIdx.x >> 1;            // 0..511

    // ---- stage W1 half (swizzled, R3-verified) ----
    for (int i = tid; i < 128 * 96; i += 256) {
        int r = i / 96, c2 = i - r * 96;
        const float* w = W1 + (size_t)(hb * 128 + r) * 192 + c2 * 2;
        sW1u[r * 96 + (c2 ^ ((r & 7) << 2))] = pk_pre(w[0], w[1]);
    }
    if (tid < 128) sB1[tid] = b1[hb * 128 + tid];

    const int lane = tid & 63;
    const int e16  = lane & 15;
    const int q    = lane >> 4;
    const int wv   = tid >> 6;
    const int l32  = lane & 31;
    const int eh   = (lane >> 5) * 8;            // scatter edge base (0 or 8)
    const int o    = wv * 32 + l32;              // scatter out-column
    const int rsw  = (e16 & 7) << 2;             // read swizzle (rows = *16+e16)

    // ---- W2 half as register-resident A-fragments (R1-verified mapping) ----
    bf16x8 w2frag[2][4];
    #pragma unroll
    for (int mtl = 0; mtl < 2; ++mtl) {
        const float* wbase = W2 + (size_t)((wv * 2 + mtl) * 16 + e16) * 256 + hb * 128 + q * 8;
        #pragma unroll
        for (int kb = 0; kb < 4; ++kb) {
            const float* wr = wbase + kb * 32;
            int4 ai;
            ai.x = (int)pk_pre(wr[0], wr[1]);
            ai.y = (int)pk_pre(wr[2], wr[3]);
            ai.z = (int)pk_pre(wr[4], wr[5]);
            ai.w = (int)pk_pre(wr[6], wr[7]);
            w2frag[mtl][kb] = __builtin_bit_cast(bf16x8, ai);
        }
    }
    const float b2o = hb ? 0.f : b2[o];

    // ---- prologue: publish idx(g0)->slot0, idx(g1)->slot1 ----
    {
        const int g0 = bseq;
        const int g1 = (bseq + 512 < 40000) ? bseq + 512 : bseq;
        if (tid < 16) {
            sSE[0][tid] = ei[g0 * 16 + tid];
            sDE[0][tid] = ei[N_EDGES + g0 * 16 + tid];
        } else if (tid < 32) {
            int t = tid - 16;
            sSE[1][t] = ei[g1 * 16 + t];
            sDE[1][t] = ei[N_EDGES + g1 * 16 + t];
        }
    }
    __syncthreads();

    // ---- prologue: stage m(g0) into sMu[0] (coalesced, R1 pattern) ----
    #pragma unroll
    for (int t = 0; t < 3; ++t) {
        int i = tid + 256 * t;
        int ee = i / 48, c4 = i - ee * 48, k = c4 * 4;
        const float* p = (k < 128)
            ? x + (size_t)sSE[0][ee] * 128 + k
            : ea + (size_t)(bseq * 16 + ee) * 64 + (k - 128);
        float4 v = *(const float4*)p;
        unsigned* mp = &sMu[0][ee * 96 + ((c4 * 2) ^ ((ee & 7) << 2))];
        mp[0] = pk_pre(v.x, v.y);
        mp[1] = pk_pre(v.z, v.w);
    }
    __syncthreads();

    int cur = 0;
    for (int g = bseq; g < 40000; g += 512, cur ^= 1) {
        const int nxt = cur ^ 1;
        const int g1v = (g + 512  < 40000) ? g + 512  : g;
        const int g2v = (g + 1024 < 40000) ? g + 1024 : g;

        // ===== P1 (pre-B1) =====
        // issue gather for m(g+1): addresses from sSE[nxt] (published last iter)
        float4 rawS[3]; int eeS[3], c4S[3];
        #pragma unroll
        for (int t = 0; t < 3; ++t) {
            int i = tid + 256 * t;
            int ee = i / 48, c4 = i - ee * 48, k = c4 * 4;
            eeS[t] = ee; c4S[t] = c4;
            const float* p = (k < 128)
                ? x + (size_t)sSE[nxt][ee] * 128 + k
                : ea + (size_t)(g1v * 16 + ee) * 64 + (k - 128);
            rawS[t] = *(const float4*)p;
        }
        // idx prefetch for g+2 (published post-B1 into slot cur)
        int i2 = 0, d2 = 0;
        if (tid < 16)       i2 = ei[g2v * 16 + tid];
        else if (tid < 32)  d2 = ei[N_EDGES + g2v * 16 + (tid - 16)];
        // pre-read this group's dst into regs (sDE[cur] is overwritten post-B1)
        const int4 dv0 = *(const int4*)&sDE[cur][eh];
        const int4 dv1 = *(const int4*)&sDE[cur][eh + 4];

        // ---- GEMM1: wave wv -> hid tiles mt = wv*2+{0,1} (reads sMu[cur]) ----
        f32x4 acc1[2];
        acc1[0] = (f32x4){0.f, 0.f, 0.f, 0.f};
        acc1[1] = (f32x4){0.f, 0.f, 0.f, 0.f};
        #pragma unroll
        for (int ks = 0; ks < 6; ++ks) {
            const int col = (ks * 16 + q * 4);
            bf16x8 bfrag = __builtin_bit_cast(bf16x8,
                *(const int4*)&sMu[cur][e16 * 96 + (col ^ rsw)]);
            #pragma unroll
            for (int mtl = 0; mtl < 2; ++mtl) {
                bf16x8 afrag = __builtin_bit_cast(bf16x8,
                    *(const int4*)&sW1u[((wv * 2 + mtl) * 16 + e16) * 96 + (col ^ rsw)]);
                acc1[mtl] = __builtin_amdgcn_mfma_f32_16x16x32_bf16(afrag, bfrag, acc1[mtl], 0, 0, 0);
            }
        }
        // epilogue: relu(+b1) -> sHu (swizzled bf16 pairs)
        #pragma unroll
        for (int mtl = 0; mtl < 2; ++mtl) {
            const int hid = (wv * 2 + mtl) * 16 + q * 4;
            float v0 = fmaxf(acc1[mtl][0] + sB1[hid + 0], 0.f);
            float v1 = fmaxf(acc1[mtl][1] + sB1[hid + 1], 0.f);
            float v2 = fmaxf(acc1[mtl][2] + sB1[hid + 2], 0.f);
            float v3 = fmaxf(acc1[mtl][3] + sB1[hid + 3], 0.f);
            unsigned* hp = &sHuU[e16 * 64 + ((hid >> 1) ^ rsw)];
            hp[0] = (unsigned)f2bf(v0) | ((unsigned)f2bf(v1) << 16);
            hp[1] = (unsigned)f2bf(v2) | ((unsigned)f2bf(v3) << 16);
        }

        BLOCK_BAR();   // B1: sHu published (lgkm only — atomics stay in flight)

        // ===== P2 (post-B1) =====
        // ---- GEMM2: wave wv -> out tiles ot = wv*2+{0,1} (reads sHu) ----
        f32x4 acc2[2];
        acc2[0] = (f32x4){0.f, 0.f, 0.f, 0.f};
        acc2[1] = (f32x4){0.f, 0.f, 0.f, 0.f};
        #pragma unroll
        for (int kb = 0; kb < 4; ++kb) {
            const int col = (kb * 16 + q * 4);
            bf16x8 bfrag = __builtin_bit_cast(bf16x8,
                *(const int4*)&sHuU[e16 * 64 + (col ^ rsw)]);
            acc2[0] = __builtin_amdgcn_mfma_f32_16x16x32_bf16(w2frag[0][kb], bfrag, acc2[0], 0, 0, 0);
            acc2[1] = __builtin_amdgcn_mfma_f32_16x16x32_bf16(w2frag[1][kb], bfrag, acc2[1], 0, 0, 0);
        }
        // write own rows of sMsg (wave-private in rows [wv*32, wv*32+32))
        #pragma unroll
        for (int mtl = 0; mtl < 2; ++mtl) {
            *(f32x4*)&sMsg[e16 * 132 + (wv * 2 + mtl) * 16 + q * 4] = acc2[mtl];
        }
        FENCE_LGKM(); SCHED_FENCE();   // intra-wave sMsg ordering only

        // scatter-read own rows: lane covers (edges eh..eh+7) x (out col o)
        float sv[8];
        #pragma unroll
        for (int j = 0; j < 8; ++j) sv[j] = sMsg[(eh + j) * 132 + o];

        // stage-write m(g+1) -> sMu[nxt] (vmcnt wait for rawS lands HERE,
        // before the atomics issue -> atomics never on the wait path)
        #pragma unroll
        for (int t = 0; t < 3; ++t) {
            unsigned* mp = &sMu[nxt][eeS[t] * 96 + ((c4S[t] * 2) ^ ((eeS[t] & 7) << 2))];
            mp[0] = pk_pre(rawS[t].x, rawS[t].y);
            mp[1] = pk_pre(rawS[t].z, rawS[t].w);
        }
        // publish idx(g+2) into slot cur (dst was pre-read before B1)
        if (tid < 16)       sSE[cur][tid] = i2;
        else if (tid < 32)  sDE[cur][tid - 16] = d2;

        // atomics: 128B-contiguous per half-wave, never waited on
        {
            const int dsts[8] = {dv0.x, dv0.y, dv0.z, dv0.w, dv1.x, dv1.y, dv1.z, dv1.w};
            #pragma unroll
            for (int j = 0; j < 8; ++j)
                unsafeAtomicAdd(out + (size_t)dsts[j] * 128 + o, sv[j] + b2o);
        }

        BLOCK_BAR();   // B2: end of iter (sMu[nxt]+idx published; lgkm only)
    }
}

extern "C" void kernel_launch(void* const* d_in, const int* in_sizes, int n_in,
                              void* d_out, int out_size, void* d_ws, size_t ws_size,
                              hipStream_t stream) {
    const float* x  = (const float*)d_in[0];
    const int*   ei = (const int*)d_in[1];
    const float* ea = (const float*)d_in[2];
    const float* W1 = (const float*)d_in[3];
    const float* b1 = (const float*)d_in[4];
    const float* W2 = (const float*)d_in[5];
    const float* b2 = (const float*)d_in[6];
    float* out = (float*)d_out;

    zero_kernel<<<1250, 256, 0, stream>>>(out);
    gine_pipe<<<1024, 256, 0, stream>>>(ei, x, ea, W1, b1, W2, b2, out);
}

// Round 7
// 722.611 us; speedup vs baseline: 3.5367x; 1.0044x over previous
//
#include <hip/hip_runtime.h>

#define N_NODES 10000
#define IN_DIM 128
#define EDGE_DIM 64
#define HID_DIM 256
#define OUT_DIM 128
#define N_EDGES 640000

// Data contract (verified R6): fp32 buffers (values bf16-rounded), int32
// edge_index, fp32 output, atomic scatter into d_out.
// R6 (resubmit; prior bench was an infra acquisition timeout, kernel never
// ran): barrier-free wave-owned pipelines. Each of 8 waves (512-thread
// block, 1/CU) owns 16 edges end-to-end:
//   - wave-cooperative coalesced gather (2x512B segs/instr) -> own sMu strip
//   - lgkm fence (wave-local ordering only; NO block barriers in loop)
//   - GEMM1 (A=W1 from LDS, 48 MFMA) -> h in regs (R3 layout)
//   - R3-PROVEN shfl realign -> h A-frags
//   - GEMM2 OPERAND-SWAPPED: msg = h @ W2^T (B=W2 from LDS, 32 MFMA)
//     -> D[edge=q*4+r][out=ot*16+e16] -> DIRECT coalesced atomics (no sMsg)
//   - gather(g+1) issued before atomics -> vmcnt in-order retire means
//     atomics are never drained.
// LDS = 49152 (W1) + 32768 (W2) + 49152 (8 strips) = 131072 B, 1 block/CU.

typedef __bf16 bf16x8 __attribute__((ext_vector_type(8)));
typedef float f32x4 __attribute__((ext_vector_type(4)));

// pre-rounded fp32 pair -> packed bf16 pair (exact: low mantissa bits are 0)
static __device__ __forceinline__ unsigned pk_pre(float lo, float hi) {
    return (__builtin_bit_cast(unsigned, lo) >> 16) |
           (__builtin_bit_cast(unsigned, hi) & 0xFFFF0000u);
}
// RNE f2bf for freshly computed values (h epilogue)
static __device__ __forceinline__ unsigned short f2bf(float f) {
    unsigned u = __builtin_bit_cast(unsigned, f);
    u = (u + 0x7fffu + ((u >> 16) & 1u)) >> 16;
    return (unsigned short)u;
}

__global__ void zero_kernel(float* __restrict__ out) {
    int t = blockIdx.x * 256 + threadIdx.x;
    if (t < 320000) ((float4*)out)[t] = make_float4(0.f, 0.f, 0.f, 0.f);
}

#define FENCE_LGKM()  asm volatile("s_waitcnt lgkmcnt(0)" ::: "memory")
#define SCHED_FENCE() __builtin_amdgcn_sched_barrier(0)

__global__ __launch_bounds__(512, 2) void gine_wave2(
    const int* __restrict__ ei,
    const float* __restrict__ x,
    const float* __restrict__ ea,
    const float* __restrict__ W1,
    const float* __restrict__ b1,
    const float* __restrict__ W2,
    const float* __restrict__ b2,
    float* __restrict__ out)
{
    // XOR-swizzled pad-free tiles (uint col ^= (row&7)<<2 keeps 16B blocks).
    __shared__ __align__(16) unsigned sW1u[128 * 96];    // 49,152 B  W1 hid-half
    __shared__ __align__(16) unsigned sW2u[128 * 64];    // 32,768 B  W2 k-half
    __shared__ __align__(16) unsigned sMu[8][16 * 96];   // 49,152 B  per-wave m strips

    const int tid  = threadIdx.x;
    const int hb   = blockIdx.x & 1;
    const int bseq = blockIdx.x >> 1;            // 0..255

    // ---- stage W1 half (swizzled, R3/R5-verified) ----
    for (int i = tid; i < 128 * 96; i += 512) {
        int r = i / 96, c2 = i - r * 96;
        const float* w = W1 + (size_t)(hb * 128 + r) * 192 + c2 * 2;
        sW1u[r * 96 + (c2 ^ ((r & 7) << 2))] = pk_pre(w[0], w[1]);
    }
    // ---- stage W2 k-half (rows = out dim) ----
    for (int i = tid; i < 128 * 64; i += 512) {
        int r = i / 64, c2 = i - r * 64;
        const float* w = W2 + (size_t)r * 256 + hb * 128 + c2 * 2;
        sW2u[r * 64 + (c2 ^ ((r & 7) << 2))] = pk_pre(w[0], w[1]);
    }

    const int lane = tid & 63;
    const int e16  = lane & 15;
    const int q    = lane >> 4;
    const int wv   = tid >> 6;                   // 0..7
    const int rsw  = (e16 & 7) << 2;             // frag-read swizzle (rows = *16+e16)
    unsigned* myM  = &sMu[wv][0];

    // ---- loop-invariant register state ----
    // b1 fragments: acc1 D-layout row = hid = mt*16+q*4+r
    f32x4 b1f[8];
    #pragma unroll
    for (int t = 0; t < 8; ++t)
        b1f[t] = *(const f32x4*)(b1 + hb * 128 + t * 16 + q * 4);
    // b2 per-lane: scatter col = ot*16 + e16 (hb==0 only)
    float b2v[8];
    #pragma unroll
    for (int t = 0; t < 8; ++t)
        b2v[t] = hb ? 0.f : b2[t * 16 + e16];

    __syncthreads();   // the only barrier: weights staged

    const int W = bseq * 8 + wv;                 // 0..2047

    // ---- prologue: idx(g0) + gather(g0) ----
    int g = W;
    int sidx = 0, didx = 0;
    if (lane < 16) {
        sidx = ei[g * 16 + lane];
        didx = ei[N_EDGES + g * 16 + lane];
    }
    float4 raw[12];
    // gather x: instr j covers rows {2j, 2j+1}, 512B contiguous per row
    #pragma unroll
    for (int j = 0; j < 8; ++j) {
        int ee = 2 * j + (lane >> 5);
        int sr = __shfl(sidx, ee, 64);
        raw[j] = *(const float4*)(x + (size_t)sr * 128 + (lane & 31) * 4);
    }
    // gather ea: instr j covers rows {4j..4j+3}, 256B contiguous per row
    #pragma unroll
    for (int j = 0; j < 4; ++j) {
        int ee = 4 * j + (lane >> 4);
        raw[8 + j] = *(const float4*)(ea + (size_t)(g * 16 + ee) * 64 + (lane & 15) * 4);
    }

    for (; g < 40000; g += 2048) {
        const int gn = (g + 2048 < 40000) ? g + 2048 : g;   // clamped prefetch

        // ---- idx(g+1): issue early (used ~GEMM1-time later) ----
        int sidx_n = 0, didx_n = 0;
        if (lane < 16) {
            sidx_n = ei[gn * 16 + lane];
            didx_n = ei[N_EDGES + gn * 16 + lane];
        }

        // ---- stage raw(g) -> own strip (vmcnt wait for raw lands here;
        //      older than this iter's atomics-to-come, in-order retire) ----
        #pragma unroll
        for (int j = 0; j < 8; ++j) {
            int ee = 2 * j + (lane >> 5);
            int c2 = ((lane & 31) * 2) ^ ((ee & 7) << 2);
            uint2 w;
            w.x = pk_pre(raw[j].x, raw[j].y);
            w.y = pk_pre(raw[j].z, raw[j].w);
            *(uint2*)&myM[ee * 96 + c2] = w;
        }
        #pragma unroll
        for (int j = 0; j < 4; ++j) {
            int ee = 4 * j + (lane >> 4);
            int c2 = 64 + (((lane & 15) * 2) ^ ((ee & 7) << 2));
            uint2 w;
            w.x = pk_pre(raw[8 + j].x, raw[8 + j].y);
            w.y = pk_pre(raw[8 + j].z, raw[8 + j].w);
            *(uint2*)&myM[ee * 96 + c2] = w;
        }
        FENCE_LGKM(); SCHED_FENCE();   // wave-local: strip writes before reads

        // ---- GEMM1: h[16 edges][128 hid-half]; A=W1 (LDS), B=m (own strip) ----
        // D: lane (e16,q) holds h[edge e16][hid mt*16+q*4+r]  [R3-verified]
        f32x4 acc1[8];
        #pragma unroll
        for (int t = 0; t < 8; ++t) acc1[t] = (f32x4){0.f, 0.f, 0.f, 0.f};
        #pragma unroll
        for (int ks = 0; ks < 6; ++ks) {
            const int col = (ks * 16 + q * 4) ^ rsw;
            bf16x8 bfrag = __builtin_bit_cast(bf16x8, *(const int4*)&myM[e16 * 96 + col]);
            #pragma unroll
            for (int mt = 0; mt < 8; ++mt) {
                bf16x8 afrag = __builtin_bit_cast(bf16x8,
                    *(const int4*)&sW1u[(mt * 16 + e16) * 96 + col]);
                acc1[mt] = __builtin_amdgcn_mfma_f32_16x16x32_bf16(afrag, bfrag, acc1[mt], 0, 0, 0);
            }
        }

        // ---- epilogue: relu(+b1) -> packed bf16 pairs (pu0=r0|r1, pu1=r2|r3) ----
        unsigned pu0[8], pu1[8];
        #pragma unroll
        for (int mt = 0; mt < 8; ++mt) {
            float v0 = fmaxf(acc1[mt][0] + b1f[mt][0], 0.f);
            float v1 = fmaxf(acc1[mt][1] + b1f[mt][1], 0.f);
            float v2 = fmaxf(acc1[mt][2] + b1f[mt][2], 0.f);
            float v3 = fmaxf(acc1[mt][3] + b1f[mt][3], 0.f);
            pu0[mt] = (unsigned)f2bf(v0) | ((unsigned)f2bf(v1) << 16);
            pu1[mt] = (unsigned)f2bf(v2) | ((unsigned)f2bf(v3) << 16);
        }

        // ---- gather(g+1) NOW (older than this iter's atomics) ----
        #pragma unroll
        for (int j = 0; j < 8; ++j) {
            int ee = 2 * j + (lane >> 5);
            int sr = __shfl(sidx_n, ee, 64);
            raw[j] = *(const float4*)(x + (size_t)sr * 128 + (lane & 31) * 4);
        }
        #pragma unroll
        for (int j = 0; j < 4; ++j) {
            int ee = 4 * j + (lane >> 4);
            raw[8 + j] = *(const float4*)(ea + (size_t)(gn * 16 + ee) * 64 + (lane & 15) * 4);
        }

        // ---- GEMM2 (operand-swapped): msg = h @ W2^T ----
        // A-frag (R3-PROVEN realign): lane (e16,q) holds h[e16][kb*32+q*8+j]
        //   j=0..3 from lane sa=(q&1)*32+e16, j=4..7 from sa+16;
        //   tile mt = 2kb + (q>>1) — TARGET's q, select AFTER shfl.
        // B-frag: W2^T[k][out] -> lane holds W2[out=ot*16+e16][k=kb*32+q*8+j]
        // D: lane (e16,q) holds msg[edge=q*4+r][out=ot*16+e16]
        f32x4 acc2[8];
        #pragma unroll
        for (int t = 0; t < 8; ++t) acc2[t] = (f32x4){0.f, 0.f, 0.f, 0.f};
        const int qh = q >> 1;
        const int sa = (q & 1) * 32 + e16;
        #pragma unroll
        for (int kb = 0; kb < 4; ++kb) {
            const int lo0 = (int)pu0[2 * kb],     lo1 = (int)pu1[2 * kb];
            const int hi0 = (int)pu0[2 * kb + 1], hi1 = (int)pu1[2 * kb + 1];
            int4 bi;
            {
                int a0 = __shfl(lo0, sa, 64),      a1 = __shfl(hi0, sa, 64);
                int b0 = __shfl(lo1, sa, 64),      b1_ = __shfl(hi1, sa, 64);
                int c0 = __shfl(lo0, sa + 16, 64), c1 = __shfl(hi0, sa + 16, 64);
                int d0 = __shfl(lo1, sa + 16, 64), d1 = __shfl(hi1, sa + 16, 64);
                bi.x = qh ? a1 : a0;
                bi.y = qh ? b1_ : b0;
                bi.z = qh ? c1 : c0;
                bi.w = qh ? d1 : d0;
            }
            bf16x8 hfrag = __builtin_bit_cast(bf16x8, bi);
            const int col = (kb * 16 + q * 4) ^ rsw;
            #pragma unroll
            for (int ot = 0; ot < 8; ++ot) {
                bf16x8 wfrag = __builtin_bit_cast(bf16x8,
                    *(const int4*)&sW2u[(ot * 16 + e16) * 64 + col]);
                acc2[ot] = __builtin_amdgcn_mfma_f32_16x16x32_bf16(hfrag, wfrag, acc2[ot], 0, 0, 0);
            }
        }

        // ---- scatter: direct coalesced atomics (64B per q-group), never waited ----
        int dr[4];
        #pragma unroll
        for (int r = 0; r < 4; ++r) dr[r] = __shfl(didx, q * 4 + r, 64);
        #pragma unroll
        for (int r = 0; r < 4; ++r) {
            float* ob = out + (size_t)dr[r] * 128 + e16;
            #pragma unroll
            for (int ot = 0; ot < 8; ++ot)
                unsafeAtomicAdd(ob + ot * 16, acc2[ot][r] + b2v[ot]);
        }

        sidx = sidx_n; didx = didx_n;
    }
}

extern "C" void kernel_launch(void* const* d_in, const int* in_sizes, int n_in,
                              void* d_out, int out_size, void* d_ws, size_t ws_size,
                              hipStream_t stream) {
    const float* x  = (const float*)d_in[0];
    const int*   ei = (const int*)d_in[1];
    const float* ea = (const float*)d_in[2];
    const float* W1 = (const float*)d_in[3];
    const float* b1 = (const float*)d_in[4];
    const float* W2 = (const float*)d_in[5];
    const float* b2 = (const float*)d_in[6];
    float* out = (float*)d_out;

    zero_kernel<<<1250, 256, 0, stream>>>(out);
    gine_wave2<<<512, 512, 0, stream>>>(ei, x, ea, W1, b1, W2, b2, out);
}